// Round 2
// baseline (328.713 us; speedup 1.0000x reference)
//
#include <hip/hip_runtime.h>
#include <hip/hip_bf16.h>

#define B_ 4
#define H_ 16
#define S_ 2048
#define D_ 64
#define QBLK 64
#define KBLK 64

typedef __attribute__((ext_vector_type(4))) float f32x4;
typedef __attribute__((ext_vector_type(8))) short s16x8;
typedef __attribute__((ext_vector_type(8))) __bf16 bf16x8;

__device__ __forceinline__ unsigned short f2bf(float f) {
    unsigned int u = __builtin_bit_cast(unsigned int, f);
    u += 0x7FFFu + ((u >> 16) & 1u);   // round-to-nearest-even
    return (unsigned short)(u >> 16);
}

__device__ __forceinline__ s16x8 cvt8(float4 a, float4 b) {
    s16x8 f;
    f[0] = (short)f2bf(a.x); f[1] = (short)f2bf(a.y);
    f[2] = (short)f2bf(a.z); f[3] = (short)f2bf(a.w);
    f[4] = (short)f2bf(b.x); f[5] = (short)f2bf(b.y);
    f[6] = (short)f2bf(b.z); f[7] = (short)f2bf(b.w);
    return f;
}

__device__ __forceinline__ f32x4 mfma_bf16(s16x8 a, s16x8 b, f32x4 c) {
    return __builtin_amdgcn_mfma_f32_16x16x32_bf16(
        __builtin_bit_cast(bf16x8, a), __builtin_bit_cast(bf16x8, b), c, 0, 0, 0);
}

__device__ __forceinline__ unsigned int pack4(int4 v) {
    return (unsigned)(v.x & 1) | ((unsigned)(v.y & 1) << 8) |
           ((unsigned)(v.z & 1) << 16) | ((unsigned)(v.w & 1) << 24);
}

__global__ __launch_bounds__(256) void attn_fwd(
    const float* __restrict__ Q, const float* __restrict__ K,
    const float* __restrict__ V, const int* __restrict__ M,
    float* __restrict__ O)
{
    // LDS: K tile [k][d] (pad 72 shorts = 144B rows, breaks bank conflicts),
    //      V tile transposed [d][k], mask bytes [q][k] (pad 80), per-wave P.
    __shared__ short k_lds[KBLK][72];
    __shared__ short v_lds[D_][72];
    __shared__ unsigned char msk_lds[QBLK][80];
    __shared__ short p_lds[4][16][72];

    const int tid = threadIdx.x;
    const int w  = tid >> 6;    // wave 0..3
    const int l  = tid & 63;
    const int lr = l & 15;      // A-row / B-col / D-col index
    const int lg = l >> 4;      // k-slice group 0..3

    const int qtile = blockIdx.x;   // 0..31
    const int bh    = blockIdx.y;   // 0..63
    const int b     = bh >> 4;      // H_ = 16
    const int qbase = qtile * QBLK;

    const float* Qp = Q + (size_t)bh * S_ * D_;
    const float* Kp = K + (size_t)bh * S_ * D_;
    const float* Vp = V + (size_t)bh * S_ * D_;
    const int* Mp = M + (size_t)b * S_ * S_;
    float* Op = O + (size_t)bh * S_ * D_;

    // ---- Q fragments (A operand), fold 1/sqrt(D) * log2(e) into Q ----
    const float qscale = 0.125f * 1.44269504088896f;
    s16x8 qfrag[2];
    {
        const int qrow = qbase + w * 16 + lr;
        for (int ks = 0; ks < 2; ++ks) {
            const float* src = Qp + (size_t)qrow * D_ + ks * 32 + lg * 8;
            float4 a = *(const float4*)(src);
            float4 c = *(const float4*)(src + 4);
            float4 as = make_float4(a.x*qscale, a.y*qscale, a.z*qscale, a.w*qscale);
            float4 cs = make_float4(c.x*qscale, c.y*qscale, c.z*qscale, c.w*qscale);
            qfrag[ks] = cvt8(as, cs);
        }
    }

    f32x4 oacc[4];
    for (int dt = 0; dt < 4; ++dt) oacc[dt] = (f32x4)(0.f);
    float mrow[4], lrow[4];
    for (int i = 0; i < 4; ++i) { mrow[i] = -1e30f; lrow[i] = 0.f; }

    for (int kb = 0; kb < S_ / KBLK; ++kb) {
        const int kbase = kb * KBLK;
        __syncthreads();   // previous iteration's LDS reads done

        // ---- stage K tile (row-major, bf16) ----
        {
            const int row = tid >> 2;
            const int dc  = (tid & 3) * 16;
            const float* src = Kp + (size_t)(kbase + row) * D_ + dc;
            float4 a0 = *(const float4*)(src + 0);
            float4 a1 = *(const float4*)(src + 4);
            float4 a2 = *(const float4*)(src + 8);
            float4 a3 = *(const float4*)(src + 12);
            *(s16x8*)&k_lds[row][dc]     = cvt8(a0, a1);
            *(s16x8*)&k_lds[row][dc + 8] = cvt8(a2, a3);
        }
        // ---- stage V transposed [d][k]: per-lane gather of 8 k for one d ----
        for (int p = 0; p < 2; ++p) {
            const int pp = w * 2 + p;              // 0..7
            const int d  = lr + (pp & 3) * 16;     // 0..63
            const int k0 = lg * 8 + (pp >> 2) * 32;
            const float* src = Vp + (size_t)(kbase + k0) * D_ + d;
            s16x8 f;
#pragma unroll
            for (int j = 0; j < 8; ++j) f[j] = (short)f2bf(src[(size_t)j * D_]);
            *(s16x8*)&v_lds[d][k0] = f;
        }
        // ---- stage mask tile: int32 (harness gives bool as int) -> bytes ----
        {
            const int row = tid >> 2;
            const int cc  = (tid & 3) * 16;
            const int* src = Mp + (size_t)(qbase + row) * S_ + kbase + cc;
            int4 a = *(const int4*)(src + 0);
            int4 bb = *(const int4*)(src + 4);
            int4 c = *(const int4*)(src + 8);
            int4 d = *(const int4*)(src + 12);
            uint4 packed;
            packed.x = pack4(a); packed.y = pack4(bb);
            packed.z = pack4(c); packed.w = pack4(d);
            *(uint4*)&msk_lds[row][cc] = packed;
        }
        __syncthreads();

        // ---- QK^T: S[16 q][64 k] per wave ----
        f32x4 sacc[4];
        for (int kt = 0; kt < 4; ++kt) sacc[kt] = (f32x4)(0.f);
#pragma unroll
        for (int ks = 0; ks < 2; ++ks) {
#pragma unroll
            for (int kt = 0; kt < 4; ++kt) {
                s16x8 kf = *(const s16x8*)&k_lds[kt * 16 + lr][ks * 32 + lg * 8];
                sacc[kt] = mfma_bf16(qfrag[ks], kf, sacc[kt]);
            }
        }

        // ---- mask + online softmax (log2 domain) ----
        float s[4][4];
#pragma unroll
        for (int kt = 0; kt < 4; ++kt)
#pragma unroll
            for (int i = 0; i < 4; ++i) {
                float sv = sacc[kt][i];
                s[kt][i] = msk_lds[w * 16 + lg * 4 + i][kt * 16 + lr] ? sv : -1e9f;
            }
#pragma unroll
        for (int i = 0; i < 4; ++i) {
            float r = fmaxf(fmaxf(s[0][i], s[1][i]), fmaxf(s[2][i], s[3][i]));
            r = fmaxf(r, __shfl_xor(r, 1));
            r = fmaxf(r, __shfl_xor(r, 2));
            r = fmaxf(r, __shfl_xor(r, 4));
            r = fmaxf(r, __shfl_xor(r, 8));
            const float mnew  = fmaxf(mrow[i], r);
            const float alpha = exp2f(mrow[i] - mnew);
            mrow[i] = mnew;
            float ps = 0.f;
#pragma unroll
            for (int kt = 0; kt < 4; ++kt) {
                float p = exp2f(s[kt][i] - mnew);
                ps += p;
                p_lds[w][lg * 4 + i][kt * 16 + lr] = (short)f2bf(p);
            }
            ps += __shfl_xor(ps, 1);
            ps += __shfl_xor(ps, 2);
            ps += __shfl_xor(ps, 4);
            ps += __shfl_xor(ps, 8);
            lrow[i] = lrow[i] * alpha + ps;
#pragma unroll
            for (int dt = 0; dt < 4; ++dt) oacc[dt][i] *= alpha;
        }
        __syncthreads();   // P visible to own-wave A-frag reads, keep waves in phase

        // ---- PV: O[16 q][64 d] += P[16][64] * V[64][64] ----
#pragma unroll
        for (int ks = 0; ks < 2; ++ks) {
            s16x8 pf = *(const s16x8*)&p_lds[w][lr][ks * 32 + lg * 8];
#pragma unroll
            for (int dt = 0; dt < 4; ++dt) {
                s16x8 vf = *(const s16x8*)&v_lds[dt * 16 + lr][ks * 32 + lg * 8];
                oacc[dt] = mfma_bf16(pf, vf, oacc[dt]);
            }
        }
    }

    // ---- epilogue: normalize and store fp32 ----
    const int orow = qbase + w * 16;
#pragma unroll
    for (int i = 0; i < 4; ++i) {
        const float inv = 1.0f / lrow[i];
#pragma unroll
        for (int dt = 0; dt < 4; ++dt) {
            Op[(size_t)(orow + lg * 4 + i) * D_ + dt * 16 + lr] = oacc[dt][i] * inv;
        }
    }
}

extern "C" void kernel_launch(void* const* d_in, const int* in_sizes, int n_in,
                              void* d_out, int out_size, void* d_ws, size_t ws_size,
                              hipStream_t stream) {
    const float* Q = (const float*)d_in[0];
    const float* K = (const float*)d_in[1];
    const float* V = (const float*)d_in[2];
    const int* M = (const int*)d_in[3];  // harness: integer/bool inputs -> const int*
    float* O = (float*)d_out;
    (void)in_sizes; (void)n_in; (void)d_ws; (void)ws_size; (void)out_size;

    dim3 grid(S_ / QBLK, B_ * H_);
    attn_fwd<<<grid, dim3(256), 0, stream>>>(Q, K, V, M, O);
}

// Round 3
// 236.118 us; speedup vs baseline: 1.3922x; 1.3922x over previous
//
#include <hip/hip_runtime.h>
#include <hip/hip_bf16.h>

#define B_ 4
#define H_ 16
#define S_ 2048
#define D_ 64
#define QBLK 64
#define KBLK 64
#define NT (S_/KBLK)

typedef __attribute__((ext_vector_type(4))) float f32x4;
typedef __attribute__((ext_vector_type(4))) unsigned int u32x4;
typedef __attribute__((ext_vector_type(8))) short s16x8;
typedef __attribute__((ext_vector_type(8))) __bf16 bf16x8;
typedef unsigned int u32;
typedef unsigned long long u64;

__device__ __forceinline__ unsigned short f2bf(float f) {
    u32 u = __builtin_bit_cast(u32, f);
    u += 0x7FFFu + ((u >> 16) & 1u);   // RNE
    return (unsigned short)(u >> 16);
}
__device__ __forceinline__ u32 pkbf(float lo, float hi) {
    return (u32)f2bf(lo) | ((u32)f2bf(hi) << 16);
}
__device__ __forceinline__ s16x8 cvt8(float4 a, float4 b) {
    s16x8 f;
    f[0] = (short)f2bf(a.x); f[1] = (short)f2bf(a.y);
    f[2] = (short)f2bf(a.z); f[3] = (short)f2bf(a.w);
    f[4] = (short)f2bf(b.x); f[5] = (short)f2bf(b.y);
    f[6] = (short)f2bf(b.z); f[7] = (short)f2bf(b.w);
    return f;
}
__device__ __forceinline__ f32x4 mfma_bf16(s16x8 a, s16x8 b, f32x4 c) {
    return __builtin_amdgcn_mfma_f32_16x16x32_bf16(
        __builtin_bit_cast(bf16x8, a), __builtin_bit_cast(bf16x8, b), c, 0, 0, 0);
}
__device__ __forceinline__ void gll16(const void* g, void* l) {
    __builtin_amdgcn_global_load_lds(
        (const __attribute__((address_space(1))) unsigned int*)g,
        (__attribute__((address_space(3))) unsigned int*)l, 16, 0, 0);
}

// ---------- pre-pass 1: K fp32 -> bf16 ----------
__global__ __launch_bounds__(256) void cvt_k(const float* __restrict__ K,
                                             short* __restrict__ Kb) {
    const int i = blockIdx.x * 256 + threadIdx.x;    // group of 8 elems
    const float4* src = (const float4*)K + (size_t)i * 2;
    float4 a = src[0], b = src[1];
    *((s16x8*)Kb + i) = cvt8(a, b);
}

// ---------- pre-pass 2: V fp32 [S][D] -> bf16 V^T [D][S] per head ----------
__global__ __launch_bounds__(256) void vt_cvt(const float* __restrict__ V,
                                              short* __restrict__ VT) {
    __shared__ float tile[64][65];
    const int bh = blockIdx.y;
    const int kc = blockIdx.x * 64;
    const int t = threadIdx.x;
    const float* src = V + (size_t)bh * S_ * D_ + (size_t)kc * D_;
#pragma unroll
    for (int p = 0; p < 4; ++p) {
        int idx = p * 256 + t;          // float4 index 0..1023
        int r = idx >> 4;
        int c = (idx & 15) * 4;
        float4 v = *(const float4*)(src + (size_t)r * D_ + c);
        tile[r][c+0] = v.x; tile[r][c+1] = v.y; tile[r][c+2] = v.z; tile[r][c+3] = v.w;
    }
    __syncthreads();
    const int d = t >> 2, c0 = (t & 3) * 16;
    s16x8 o0, o1;
#pragma unroll
    for (int j = 0; j < 8; ++j) {
        o0[j] = (short)f2bf(tile[c0 + j][d]);
        o1[j] = (short)f2bf(tile[c0 + 8 + j][d]);
    }
    short* dst = VT + (size_t)bh * D_ * S_ + (size_t)d * S_ + kc + c0;
    *(s16x8*)dst = o0;
    *(s16x8*)(dst + 8) = o1;
}

// ---------- pre-pass 3: int32 mask -> bitmask (1 bit per element) ----------
__global__ __launch_bounds__(256) void mk_bits(const int* __restrict__ M,
                                               u64* __restrict__ Mb) {
    const int wid = blockIdx.x * 4 + (threadIdx.x >> 6);
    const int l = threadIdx.x & 63;
    const int nw = gridDim.x * 4;
    const int total = B_ * S_ * (S_ / 64);
    for (int g = wid; g < total; g += nw) {
        int m = M[(size_t)g * 64 + l];
        u64 bal = __ballot(m != 0);
        if (l == 0) Mb[g] = bal;
    }
}

// ---------- main fused attention ----------
__global__ __launch_bounds__(256) void attn_fwd(
    const float* __restrict__ Q, const short* __restrict__ Kb,
    const short* __restrict__ VTb, const u64* __restrict__ Mb,
    float* __restrict__ O)
{
    __shared__ short kbuf[2][KBLK * D_];   // linear, granule-swizzled
    __shared__ short vbuf[2][KBLK * D_];

    const int tid = threadIdx.x;
    const int w  = tid >> 6;
    const int l  = tid & 63;
    const int lr = l & 15;
    const int lg = l >> 4;

    // XCD-aware decode: 8 heads per XCD (dispatch d -> XCD d%8)
    const int dd    = blockIdx.x;
    const int xcd   = dd & 7;
    const int slot  = dd >> 3;
    const int bh    = xcd * 8 + (slot >> 5);
    const int qtile = slot & 31;
    const int b     = bh >> 4;
    const int qbase = qtile * QBLK;

    const float* Qp = Q   + (size_t)bh * S_ * D_;
    const short* Kp = Kb  + (size_t)bh * S_ * D_;
    const short* Vp = VTb + (size_t)bh * D_ * S_;
    const u64*   Mp = Mb  + ((size_t)b * S_ + qbase + w * 16 + lr) * (S_ / 64);
    float* Op = O + (size_t)bh * S_ * D_;

    // Q B-fragments (scale * log2e folded)
    const float qscale = 0.125f * 1.44269504088896f;
    s16x8 qfrag[2];
    {
        const float* src = Qp + (size_t)(qbase + w * 16 + lr) * D_ + lg * 8;
#pragma unroll
        for (int ks = 0; ks < 2; ++ks) {
            float4 a = *(const float4*)(src + ks * 32);
            float4 c = *(const float4*)(src + ks * 32 + 4);
            float4 as = make_float4(a.x*qscale, a.y*qscale, a.z*qscale, a.w*qscale);
            float4 cs = make_float4(c.x*qscale, c.y*qscale, c.z*qscale, c.w*qscale);
            qfrag[ks] = cvt8(as, cs);
        }
    }

    // staging lane constants: rows w*16+t*8+(l>>3), LDS pos p=l&7, src granule p^(row&7)
    const int srow = w * 16 + (l >> 3);
    const int sg   = (l & 7) ^ (l >> 3);
    const char* KsrcB = (const char*)Kp + (size_t)srow * 128 + sg * 16;
    const char* VsrcB = (const char*)Vp + (size_t)srow * (S_ * 2) + sg * 16;

    // swizzled read offsets (row = kt*16+lr, granule g=ks*4+lg at pos g^(lr&7))
    const int offs0 = lr * 128 + (((lg    ) ^ (lr & 7)) << 4);
    const int offs1 = lr * 128 + (((lg + 4) ^ (lr & 7)) << 4);

    f32x4 oacc[4];
#pragma unroll
    for (int dt = 0; dt < 4; ++dt) oacc[dt] = (f32x4)(0.f);
    float mrow = -1e30f, lrowv = 0.f;

    const int gb   = l & 48;                       // lane-group base
    const int srcA = (((lg * 2    ) & 3) << 4) | lr;
    const int srcB = (((lg * 2 + 1) & 3) << 4) | lr;
    const int hi2  = lg >> 1;

    // prologue: stage tile 0 into buf 0
    {
        short* kd = &kbuf[0][(w * 16) * 64];
        short* vd = &vbuf[0][(w * 16) * 64];
        gll16(KsrcB,            kd);
        gll16(KsrcB + 1024,     kd + 8 * 64);
        gll16(VsrcB,            vd);
        gll16(VsrcB + 8 * 4096, vd + 8 * 64);
    }

    for (int t = 0; t < NT; ++t) {
        const int cur = t & 1;
        asm volatile("s_waitcnt vmcnt(0)" ::: "memory");
        __syncthreads();
        if (t + 1 < NT) {
            const int kb2 = (t + 1) * KBLK;
            short* kd = &kbuf[cur ^ 1][(w * 16) * 64];
            short* vd = &vbuf[cur ^ 1][(w * 16) * 64];
            gll16(KsrcB + (size_t)kb2 * 128,            kd);
            gll16(KsrcB + (size_t)kb2 * 128 + 1024,     kd + 8 * 64);
            gll16(VsrcB + (size_t)kb2 * 2,              vd);
            gll16(VsrcB + (size_t)kb2 * 2 + 8 * 4096,   vd + 8 * 64);
        }
        const u64 mb = Mp[t];

        // ---- QK^T (swapped): sacc[kt] = S^T[k=kt*16+lg*4+i][q=lr] ----
        const char* kbp = (const char*)kbuf[cur];
        f32x4 sacc[4];
#pragma unroll
        for (int kt = 0; kt < 4; ++kt) sacc[kt] = (f32x4)(0.f);
#pragma unroll
        for (int ks = 0; ks < 2; ++ks) {
            const int off = ks ? offs1 : offs0;
#pragma unroll
            for (int kt = 0; kt < 4; ++kt) {
                s16x8 kf = *(const s16x8*)(kbp + kt * 2048 + off);
                sacc[kt] = mfma_bf16(kf, qfrag[ks], sacc[kt]);
            }
        }

        // ---- mask + lane-local online softmax ----
        const u32 mlo = (u32)(mb >> (lg * 4));
        const u32 mhi = (u32)(mb >> (32 + lg * 4));
        float s[4][4];
        float mx = -1e30f;
#pragma unroll
        for (int kt = 0; kt < 4; ++kt) {
            const u32 mm = (kt < 2) ? mlo : mhi;
            const int sh = (kt & 1) * 16;
#pragma unroll
            for (int i = 0; i < 4; ++i) {
                float v = sacc[kt][i];
                s[kt][i] = ((mm >> (sh + i)) & 1u) ? v : -1e9f;
                mx = fmaxf(mx, s[kt][i]);
            }
        }
        mx = fmaxf(mx, __shfl_xor(mx, 16));
        mx = fmaxf(mx, __shfl_xor(mx, 32));
        const float mnew  = fmaxf(mrow, mx);
        const float alpha = exp2f(mrow - mnew);
        mrow = mnew;

        float ps = 0.f;
        u32 pk[4][2];
#pragma unroll
        for (int kt = 0; kt < 4; ++kt) {
            float p0 = exp2f(s[kt][0] - mnew), p1 = exp2f(s[kt][1] - mnew);
            float p2 = exp2f(s[kt][2] - mnew), p3 = exp2f(s[kt][3] - mnew);
            ps += (p0 + p1) + (p2 + p3);
            pk[kt][0] = pkbf(p0, p1);
            pk[kt][1] = pkbf(p2, p3);
        }
        ps += __shfl_xor(ps, 16);
        ps += __shfl_xor(ps, 32);
        lrowv = lrowv * alpha + ps;

        // ---- rescale O by per-row alpha (broadcast from lane lr=q) ----
#pragma unroll
        for (int i = 0; i < 4; ++i) {
            float ai = __shfl(alpha, gb + lg * 4 + i);
#pragma unroll
            for (int dt = 0; dt < 4; ++dt) oacc[dt][i] *= ai;
        }

        // ---- redistribute P into PV A-fragments (in-register) ----
        u32 pa[2][4];
#pragma unroll
        for (int ks = 0; ks < 2; ++ks) {
#pragma unroll
            for (int h = 0; h < 2; ++h) {
                u32 e0a = __shfl(pk[ks * 2    ][h], srcA);
                u32 e0b = __shfl(pk[ks * 2    ][h], srcB);
                u32 e1a = __shfl(pk[ks * 2 + 1][h], srcA);
                u32 e1b = __shfl(pk[ks * 2 + 1][h], srcB);
                pa[ks][h]     = hi2 ? e1a : e0a;
                pa[ks][h + 2] = hi2 ? e1b : e0b;
            }
        }

        // ---- PV ----
        const char* vbp = (const char*)vbuf[cur];
#pragma unroll
        for (int ks = 0; ks < 2; ++ks) {
            u32x4 pv = {pa[ks][0], pa[ks][1], pa[ks][2], pa[ks][3]};
            s16x8 paf = __builtin_bit_cast(s16x8, pv);
            const int off = ks ? offs1 : offs0;
#pragma unroll
            for (int dt = 0; dt < 4; ++dt) {
                s16x8 vf = *(const s16x8*)(vbp + dt * 2048 + off);
                oacc[dt] = mfma_bf16(paf, vf, oacc[dt]);
            }
        }
    }

    // ---- epilogue ----
#pragma unroll
    for (int i = 0; i < 4; ++i) {
        float li = __shfl(lrowv, gb + lg * 4 + i);
        float inv = 1.0f / li;
        const int qrow = qbase + w * 16 + lg * 4 + i;
#pragma unroll
        for (int dt = 0; dt < 4; ++dt)
            Op[(size_t)qrow * D_ + dt * 16 + lr] = oacc[dt][i] * inv;
    }
}

extern "C" void kernel_launch(void* const* d_in, const int* in_sizes, int n_in,
                              void* d_out, int out_size, void* d_ws, size_t ws_size,
                              hipStream_t stream) {
    const float* Q = (const float*)d_in[0];
    const float* K = (const float*)d_in[1];
    const float* V = (const float*)d_in[2];
    const int*   M = (const int*)d_in[3];
    float* O = (float*)d_out;
    (void)in_sizes; (void)n_in; (void)out_size;

    char* ws = (char*)d_ws;
    short* Kb  = (short*)(ws);                          // 16,777,216 B
    short* VTb = (short*)(ws + 16777216);               // 16,777,216 B
    u64*   Mb  = (u64*)  (ws + 33554432);               //  2,097,152 B
    (void)ws_size;

    cvt_k  <<<4096, 256, 0, stream>>>(K, Kb);
    vt_cvt <<<dim3(S_ / 64, B_ * H_), 256, 0, stream>>>(V, VTb);
    mk_bits<<<1024, 256, 0, stream>>>(M, Mb);
    attn_fwd<<<2048, 256, 0, stream>>>(Q, Kb, VTb, Mb, O);
}

// Round 6
// 174.849 us; speedup vs baseline: 1.8800x; 1.3504x over previous
//
#include <hip/hip_runtime.h>
#include <hip/hip_bf16.h>

#define B_ 4
#define H_ 16
#define S_ 2048
#define D_ 64
#define KBLK 64
#define NT (S_/KBLK)

typedef __attribute__((ext_vector_type(4)))  float f32x4;
typedef __attribute__((ext_vector_type(16))) float f32x16;
typedef __attribute__((ext_vector_type(4)))  unsigned int u32x4;
typedef __attribute__((ext_vector_type(8)))  short s16x8;
typedef __attribute__((ext_vector_type(8)))  __bf16 bf16x8;
typedef unsigned int u32;
typedef unsigned long long u64;

__device__ __forceinline__ unsigned short f2bf(float f) {
    u32 u = __builtin_bit_cast(u32, f);
    u += 0x7FFFu + ((u >> 16) & 1u);   // RNE
    return (unsigned short)(u >> 16);
}
__device__ __forceinline__ s16x8 cvt8(float4 a, float4 b) {
    s16x8 f;
    f[0] = (short)f2bf(a.x); f[1] = (short)f2bf(a.y);
    f[2] = (short)f2bf(a.z); f[3] = (short)f2bf(a.w);
    f[4] = (short)f2bf(b.x); f[5] = (short)f2bf(b.y);
    f[6] = (short)f2bf(b.z); f[7] = (short)f2bf(b.w);
    return f;
}
__device__ __forceinline__ f32x16 mfma32(s16x8 a, s16x8 b, f32x16 c) {
    return __builtin_amdgcn_mfma_f32_32x32x16_bf16(
        __builtin_bit_cast(bf16x8, a), __builtin_bit_cast(bf16x8, b), c, 0, 0, 0);
}
__device__ __forceinline__ void gll16(const void* g, void* l) {
    __builtin_amdgcn_global_load_lds(
        (const __attribute__((address_space(1))) unsigned int*)g,
        (__attribute__((address_space(3))) unsigned int*)l, 16, 0, 0);
}
__device__ __forceinline__ u32 pkcvt(float lo, float hi) {
    u32 r;
    asm("v_cvt_pk_bf16_f32 %0, %1, %2" : "=v"(r) : "v"(lo), "v"(hi));
    return r;
}

// ---------- pre-pass 1: K fp32 -> bf16 ----------
__global__ __launch_bounds__(256) void cvt_k(const float* __restrict__ K,
                                             short* __restrict__ Kb) {
    const int i = blockIdx.x * 256 + threadIdx.x;
    const float4* src = (const float4*)K + (size_t)i * 2;
    float4 a = src[0], b = src[1];
    *((s16x8*)Kb + i) = cvt8(a, b);
}

// ---------- pre-pass 2: V fp32 [S][D] -> bf16 V^T [D][S] per head ----------
__global__ __launch_bounds__(256) void vt_cvt(const float* __restrict__ V,
                                              short* __restrict__ VT) {
    __shared__ float tile[64][65];
    const int bh = blockIdx.y;
    const int kc = blockIdx.x * 64;
    const int t = threadIdx.x;
    const float* src = V + (size_t)bh * S_ * D_ + (size_t)kc * D_;
#pragma unroll
    for (int p = 0; p < 4; ++p) {
        int idx = p * 256 + t;
        int r = idx >> 4;
        int c = (idx & 15) * 4;
        float4 v = *(const float4*)(src + (size_t)r * D_ + c);
        tile[r][c+0] = v.x; tile[r][c+1] = v.y; tile[r][c+2] = v.z; tile[r][c+3] = v.w;
    }
    __syncthreads();
    const int d = t >> 2, c0 = (t & 3) * 16;
    s16x8 o0, o1;
#pragma unroll
    for (int j = 0; j < 8; ++j) {
        o0[j] = (short)f2bf(tile[c0 + j][d]);
        o1[j] = (short)f2bf(tile[c0 + 8 + j][d]);
    }
    short* dst = VT + (size_t)bh * D_ * S_ + (size_t)d * S_ + kc + c0;
    *(s16x8*)dst = o0;
    *(s16x8*)(dst + 8) = o1;
}

// ---------- pre-pass 3: int32 mask -> bitmask ----------
__global__ __launch_bounds__(256) void mk_bits(const int* __restrict__ M,
                                               u64* __restrict__ Mb) {
    const int wid = blockIdx.x * 4 + (threadIdx.x >> 6);
    const int l = threadIdx.x & 63;
    const int nw = gridDim.x * 4;
    const int total = B_ * S_ * (S_ / 64);
    for (int g = wid; g < total; g += nw) {
        int m = M[(size_t)g * 64 + l];
        u64 bal = __ballot(m != 0);
        if (l == 0) Mb[g] = bal;
    }
}

// ---------- main fused attention: 4 waves x 32 q-rows, 32x32 swapped ----------
__global__ __launch_bounds__(256) void attn_fwd(
    const float* __restrict__ Q, const short* __restrict__ Kb,
    const short* __restrict__ VTb, const u64* __restrict__ Mb,
    float* __restrict__ O)
{
    __shared__ short kbuf[2][KBLK * D_];   // 64 rows x 128B, granule-swizzled
    __shared__ short vbuf[2][KBLK * D_];   // 64 d-rows x 128B

    const int tid = threadIdx.x;
    const int w  = tid >> 6;
    const int l  = tid & 63;
    const int ql = l & 31;       // q within wave tile / k-row / d-row
    const int h  = l >> 5;       // lane half
    const int m7 = l & 7;

    // XCD-aware decode: 1024 blocks, 8 heads per XCD
    const int dd    = blockIdx.x;
    const int xcd   = dd & 7;
    const int slot  = dd >> 3;           // 0..127
    const int bh    = xcd * 8 + (slot >> 4);
    const int qtile = slot & 15;
    const int b     = bh >> 4;
    const int qbase = qtile * 128;
    const int qrow  = qbase + w * 32 + ql;

    const float* Qp = Q   + (size_t)bh * S_ * D_;
    const short* Kp = Kb  + (size_t)bh * S_ * D_;
    const short* Vp = VTb + (size_t)bh * D_ * S_;
    const u64*   Mp = Mb  + ((size_t)b * S_ + qrow) * (S_ / 64);
    float* Op = O + (size_t)bh * S_ * D_;

    // ---- Q fragments (B operand): qfrag[ks] = Q[qrow][ks*16 + h*8 + j] * scale
    const float qscale = 0.125f * 1.44269504088896f;   // 1/sqrt(64) * log2(e)
    s16x8 qfrag[4];
#pragma unroll
    for (int ks = 0; ks < 4; ++ks) {
        const float* src = Qp + (size_t)qrow * D_ + ks * 16 + h * 8;
        float4 a = *(const float4*)(src);
        float4 c = *(const float4*)(src + 4);
        float4 as = make_float4(a.x*qscale, a.y*qscale, a.z*qscale, a.w*qscale);
        float4 cs = make_float4(c.x*qscale, c.y*qscale, c.z*qscale, c.w*qscale);
        qfrag[ks] = cvt8(as, cs);
    }

    // ---- LDS read offsets (shared by K and V reads): row = blk*32+ql
    int offs[2][4];
#pragma unroll
    for (int bk = 0; bk < 2; ++bk)
#pragma unroll
        for (int ks = 0; ks < 4; ++ks)
            offs[bk][ks] = (bk * 32 + ql) * 128 + (((ks * 2 + h) ^ m7) << 4);

    // ---- staging constants (both-sides granule swizzle, verified round 3)
    const int srow = w * 16 + (l >> 3);
    const int sg   = m7 ^ (l >> 3);
    const char* KsrcB = (const char*)Kp + (size_t)srow * 128 + sg * 16;
    const char* VsrcB = (const char*)Vp + (size_t)srow * (S_ * 2) + sg * 16;

    f32x16 oaccT[2];
    oaccT[0] = (f32x16)(0.f); oaccT[1] = (f32x16)(0.f);
    float mrun = -1e30f, lh = 0.f;

    // prologue: stage tile 0 into buf 0
    {
        short* kd = &kbuf[0][(w * 16) * 64];
        short* vd = &vbuf[0][(w * 16) * 64];
        gll16(KsrcB,            kd);
        gll16(KsrcB + 1024,     kd + 8 * 64);
        gll16(VsrcB,            vd);
        gll16(VsrcB + 8 * 4096, vd + 8 * 64);
    }

    for (int t = 0; t < NT; ++t) {
        const int cur = t & 1;
        asm volatile("s_waitcnt vmcnt(0)" ::: "memory");
        __syncthreads();
        if (t + 1 < NT) {
            short* kd = &kbuf[cur ^ 1][(w * 16) * 64];
            short* vd = &vbuf[cur ^ 1][(w * 16) * 64];
            gll16(KsrcB + (size_t)(t + 1) * 8192,       kd);
            gll16(KsrcB + (size_t)(t + 1) * 8192 + 1024, kd + 8 * 64);
            gll16(VsrcB + (size_t)(t + 1) * 128,        vd);
            gll16(VsrcB + (size_t)(t + 1) * 128 + 8 * 4096, vd + 8 * 64);
        }
        const u64 mb = Mp[t];

        // ---- QK^T swapped: lane owns q-col ql; regs = 16 k-rows per 32-block
        const char* kbp = (const char*)kbuf[cur];
        f32x16 sacc0 = (f32x16)(0.f), sacc1 = (f32x16)(0.f);
#pragma unroll
        for (int ks = 0; ks < 4; ++ks)
            sacc0 = mfma32(*(const s16x8*)(kbp + offs[0][ks]), qfrag[ks], sacc0);
#pragma unroll
        for (int ks = 0; ks < 4; ++ks)
            sacc1 = mfma32(*(const s16x8*)(kbp + offs[1][ks]), qfrag[ks], sacc1);

        // ---- mask (k = (i&3)+8*(i>>2)+4h within each 32-block) ----
        const u32 w0 = (u32)mb, w1 = (u32)(mb >> 32);
        const u32 wh0 = h ? (w0 >> 4) : w0;
        const u32 wh1 = h ? (w1 >> 4) : w1;
        float s0[16], s1[16];
#pragma unroll
        for (int i = 0; i < 16; ++i) {
            const int ci = (i & 3) + 8 * (i >> 2);
            s0[i] = ((wh0 >> ci) & 1u) ? sacc0[i] : -1e9f;
            s1[i] = ((wh1 >> ci) & 1u) ? sacc1[i] : -1e9f;
        }

        // ---- row max: lane-local + cross-half via shfl_xor(32) ----
        float pm = s0[0];
#pragma unroll
        for (int i = 1; i < 16; ++i) pm = fmaxf(pm, s0[i]);
#pragma unroll
        for (int i = 0; i < 16; ++i) pm = fmaxf(pm, s1[i]);
        pm = fmaxf(pm, __shfl_xor(pm, 32));

        // ---- deferred rescale (T13, THR=8 in log2 domain) ----
        if (!__all(pm - mrun <= 8.0f)) {
            const float mnew = fmaxf(mrun, pm);
            const float a = __builtin_amdgcn_exp2f(mrun - mnew);
            lh *= a;
#pragma unroll
            for (int dt = 0; dt < 2; ++dt)
#pragma unroll
                for (int i = 0; i < 16; ++i) oaccT[dt][i] *= a;
            mrun = mnew;
        }

        // ---- p = exp2(s - m), pack to bf16 pairs, accumulate sum ----
        float ps = 0.f;
        u32 pk0[8], pk1[8];
#pragma unroll
        for (int j = 0; j < 8; ++j) {
            float a0 = __builtin_amdgcn_exp2f(s0[2*j]   - mrun);
            float a1 = __builtin_amdgcn_exp2f(s0[2*j+1] - mrun);
            ps += a0 + a1;
            pk0[j] = pkcvt(a0, a1);
        }
#pragma unroll
        for (int j = 0; j < 8; ++j) {
            float a0 = __builtin_amdgcn_exp2f(s1[2*j]   - mrun);
            float a1 = __builtin_amdgcn_exp2f(s1[2*j+1] - mrun);
            ps += a0 + a1;
            pk1[j] = pkcvt(a0, a1);
        }
        lh += ps;

        // ---- in-register transpose to PV B-frags (distinct regs, no CSE) ----
        asm("v_permlane32_swap_b32 %0, %1" : "+v"(pk0[0]), "+v"(pk0[2]));
        asm("v_permlane32_swap_b32 %0, %1" : "+v"(pk0[1]), "+v"(pk0[3]));
        asm("v_permlane32_swap_b32 %0, %1" : "+v"(pk0[4]), "+v"(pk0[6]));
        asm("v_permlane32_swap_b32 %0, %1" : "+v"(pk0[5]), "+v"(pk0[7]));
        asm("v_permlane32_swap_b32 %0, %1" : "+v"(pk1[0]), "+v"(pk1[2]));
        asm("v_permlane32_swap_b32 %0, %1" : "+v"(pk1[1]), "+v"(pk1[3]));
        asm("v_permlane32_swap_b32 %0, %1" : "+v"(pk1[4]), "+v"(pk1[6]));
        asm("v_permlane32_swap_b32 %0, %1" : "+v"(pk1[5]), "+v"(pk1[7]));

        s16x8 pfrag[4];
        {
            u32x4 f0 = {pk0[0], pk0[1], pk0[2], pk0[3]};
            u32x4 f1 = {pk0[4], pk0[5], pk0[6], pk0[7]};
            u32x4 f2 = {pk1[0], pk1[1], pk1[2], pk1[3]};
            u32x4 f3 = {pk1[4], pk1[5], pk1[6], pk1[7]};
            pfrag[0] = __builtin_bit_cast(s16x8, f0);
            pfrag[1] = __builtin_bit_cast(s16x8, f1);
            pfrag[2] = __builtin_bit_cast(s16x8, f2);
            pfrag[3] = __builtin_bit_cast(s16x8, f3);
        }

        // ---- PV: O^T[d][q] += V^T[d][k] * P^T[k][q] ----
        const char* vbp = (const char*)vbuf[cur];
#pragma unroll
        for (int ks = 0; ks < 4; ++ks) {
#pragma unroll
            for (int dt = 0; dt < 2; ++dt) {
                s16x8 vf = *(const s16x8*)(vbp + offs[dt][ks]);
                oaccT[dt] = mfma32(vf, pfrag[ks], oaccT[dt]);
            }
        }
    }

    // ---- epilogue: combine half-sums via shfl_xor(32), normalize, store ----
    lh += __shfl_xor(lh, 32);
    const float inv = 1.0f / lh;
#pragma unroll
    for (int dt = 0; dt < 2; ++dt) {
#pragma unroll
        for (int rg = 0; rg < 4; ++rg) {
            float4 st;
            st.x = oaccT[dt][rg*4+0] * inv;
            st.y = oaccT[dt][rg*4+1] * inv;
            st.z = oaccT[dt][rg*4+2] * inv;
            st.w = oaccT[dt][rg*4+3] * inv;
            *(float4*)(Op + (size_t)qrow * D_ + dt * 32 + rg * 8 + h * 4) = st;
        }
    }
}

extern "C" void kernel_launch(void* const* d_in, const int* in_sizes, int n_in,
                              void* d_out, int out_size, void* d_ws, size_t ws_size,
                              hipStream_t stream) {
    const float* Q = (const float*)d_in[0];
    const float* K = (const float*)d_in[1];
    const float* V = (const float*)d_in[2];
    const int*   M = (const int*)d_in[3];
    float* O = (float*)d_out;
    (void)in_sizes; (void)n_in; (void)out_size; (void)ws_size;

    char* ws = (char*)d_ws;
    short* Kb  = (short*)(ws);
    short* VTb = (short*)(ws + 16777216);
    u64*   Mb  = (u64*)  (ws + 33554432);

    cvt_k  <<<4096, 256, 0, stream>>>(K, Kb);
    vt_cvt <<<dim3(S_ / 64, B_ * H_), 256, 0, stream>>>(V, VTb);
    mk_bits<<<1024, 256, 0, stream>>>(M, Mb);
    attn_fwd<<<1024, 256, 0, stream>>>(Q, Kb, VTb, Mb, O);
}